// Round 1
// baseline (477.748 us; speedup 1.0000x reference)
//
#include <hip/hip_runtime.h>
#include <stdint.h>
#include <stddef.h>

// SplitConv4Pim forward on MI355X.
// Reference = 1024-channel 3x3 conv (all 4 groups share the same input) with
// 2-bit-slice weight quantization and per-group psum quantization.
//
// ws layout: [wq bf16: 1024*9*256*2 = 4,718,592 B][xt bf16: 16*58*58*256*2 = 27,557,888 B]
// total ws need = 32,276,480 B.

typedef __bf16 bf16_t;
typedef __bf16 bf16x8 __attribute__((ext_vector_type(8)));
typedef float  f32x4  __attribute__((ext_vector_type(4)));

#define WS_XT_OFF 4718592

__device__ __forceinline__ void gload16(const void* g, void* l) {
  __builtin_amdgcn_global_load_lds(
      (const __attribute__((address_space(1))) uint32_t*)g,
      (__attribute__((address_space(3))) uint32_t*)l, 16, 0, 0);
}

// ---- P1: weight quantization: w[o][ic][ky][kx] f32 -> wq[o][kpos][ic] bf16 ----
__global__ void quant_w_k(const float* __restrict__ w,
                          const float* __restrict__ wsc,
                          bf16_t* __restrict__ wqo) {
  int idx = blockIdx.x * 256 + threadIdx.x;   // exactly 1024*9*256 threads
  int ic   = idx & 255;
  int t2   = idx >> 8;
  int kpos = t2 % 9;
  int o    = t2 / 9;
  float s  = wsc[ic >> 5];                    // per-32-ic col_slide scale
  float wv = w[o * 2304 + ic * 9 + kpos];
  float wi = rintf(wv / s);                   // jnp.round = RNE = rintf
  wi = fminf(127.f, fmaxf(-128.f, wi));
  int u = (int)wi + 128;                      // unsigned code in [0,255]
  int q = (u >> 6) & 3;                       // bit-slice (shift=64, mask=4)
  float wsplit = (float)(q * 64 - 128);       // minus `move` (IDX==0)
  wqo[idx] = (bf16_t)(wsplit * s);
}

// ---- P2: x NCHW f32 -> padded NHWC bf16 xt[16][58][58][256] ----
__global__ void pad_x_k(const float* __restrict__ x, bf16_t* __restrict__ xt) {
  __shared__ bf16_t tile[56 * 258];           // [x][c], stride 258 kills bank conflicts
  int b  = blockIdx.x / 58;
  int yo = blockIdx.x % 58;
  int t  = threadIdx.x;                       // 256 threads
  bf16_t* dst = xt + (size_t)(b * 58 + yo) * 58 * 256;
  if (yo == 0 || yo == 57) {                  // top/bottom pad rows
    for (int i = 0; i < 58; ++i) dst[i * 256 + t] = (bf16_t)0.0f;
    return;
  }
  const float* src = x + (size_t)b * 256 * 3136 + (yo - 1) * 56;  // + c*3136 + xx
  for (int i = 0; i < 56 * 256; i += 256) {
    int lin = i + t;
    int c  = lin / 56;
    int xx = lin - c * 56;
    tile[xx * 258 + c] = (bf16_t)src[c * 3136 + xx];
  }
  __syncthreads();
  for (int xo = 0; xo < 58; ++xo) {
    bf16_t v = (bf16_t)0.0f;
    if (xo >= 1 && xo <= 56) v = tile[(xo - 1) * 258 + t];
    dst[xo * 256 + t] = v;                    // coalesced 512B stores
  }
}

// ---- main: implicit-GEMM conv + per-group psum quant + group sum ----
// grid: 392 m-tiles * 2 oc-tiles = 784 blocks, 256 threads (4 waves, 2x2 of 64x64).
__global__ __launch_bounds__(256, 2)
void conv_q_k(const bf16_t* __restrict__ xt, const bf16_t* __restrict__ wq,
              const float* __restrict__ ps, float* __restrict__ out) {
  __shared__ alignas(16) bf16_t Ab[2][4096];  // weights tile [128 oc][32 k], dbuf
  __shared__ alignas(16) bf16_t Bb[2][4096];  // input   tile [128 m ][32 k], dbuf

  const int tid  = threadIdx.x;
  const int lane = tid & 63;
  const int wave = tid >> 6;
  const int n0 = (blockIdx.x & 1) << 7;                 // oc tile base (0 or 128)
  const int m0 = (int)(blockIdx.x >> 1) << 7;           // m tile base

  // ---- staging thread mapping: chunk c = tid (+256); row = c>>2, 16B sub = c&3 ----
  const int r0   = tid >> 2;
  const int subo = (tid & 3) << 3;                      // element offset of 16B chunk
  int rb0, rb1;                                         // input row base offsets (elems)
  {
    int gm = m0 + r0;
    int b = gm / 3136, rem = gm - b * 3136;
    int oy = rem / 56, ox = rem - oy * 56;
    rb0 = ((b * 58 + oy) * 58 + ox) << 8;
    gm += 64;
    b = gm / 3136; rem = gm - b * 3136;
    oy = rem / 56; ox = rem - oy * 56;
    rb1 = ((b * 58 + oy) * 58 + ox) << 8;
  }
  const int wrow0 = (n0 + r0) * 2304;                   // weight row bases (elems)
  const int wrow1 = wrow0 + 64 * 2304;
  char* const laA = (char*)&Ab[0][0] + wave * 1024;     // wave-uniform LDS dests
  char* const laB = (char*)&Bb[0][0] + wave * 1024;

  // ---- compute mapping ----
  const int wr = wave >> 1, wc = wave & 1;
  const int rr = lane & 15;
  const int ko = (lane >> 4) << 3;                      // k sub-block 0/8/16/24
  const int aoff = (wr * 64 + rr) * 32 + ko;
  const int boff = (wc * 64 + rr) * 32 + ko;

  f32x4 acc[4][4], oacc[4][4];
#pragma unroll
  for (int i = 0; i < 4; ++i)
#pragma unroll
    for (int j = 0; j < 4; ++j)
#pragma unroll
      for (int k = 0; k < 4; ++k) { acc[i][j][k] = 0.f; oacc[i][j][k] = 0.f; }

  auto STAGE = [&](int gg, int kk, int buf) {
    const int kpos = kk >> 3;                 // tap index 0..8
    const int icb  = kk & 7;                  // 32-ic block 0..7
    const int ky = kpos / 3;
    const int kx = kpos - ky * 3;
    const int cm   = (icb << 5) + subo;
    const int woff = gg * 589824 + kpos * 256 + cm;     // gg*256*2304
    const int xoff = ((ky * 58 + kx) << 8) + cm;
    char* la = laA + buf * 8192;
    char* lb = laB + buf * 8192;
    gload16(wq + wrow0 + woff, la);
    gload16(wq + wrow1 + woff, la + 4096);
    gload16(xt + rb0 + xoff, lb);
    gload16(xt + rb1 + xoff, lb + 4096);
  };

  STAGE(0, 0, 0);

#pragma unroll 1
  for (int g = 0; g < 4; ++g) {
#pragma unroll 2
    for (int kk = 0; kk < 72; ++kk) {
      const int buf = kk & 1;
      __syncthreads();                        // drains vmcnt: buf staged, buf^1 free
      if (kk + 1 < 72)      STAGE(g, kk + 1, buf ^ 1);
      else if (g < 3)       STAGE(g + 1, 0, buf ^ 1);
      const bf16_t* Abase = &Ab[buf][aoff];
      const bf16_t* Bbase = &Bb[buf][boff];
      bf16x8 av[4], bv[4];
#pragma unroll
      for (int i = 0; i < 4; ++i) {
        av[i] = *(const bf16x8*)(Abase + i * 512);      // ds_read_b128
        bv[i] = *(const bf16x8*)(Bbase + i * 512);
      }
#pragma unroll
      for (int i = 0; i < 4; ++i)
#pragma unroll
        for (int j = 0; j < 4; ++j)
          acc[i][j] = __builtin_amdgcn_mfma_f32_16x16x32_bf16(av[i], bv[j], acc[i][j], 0, 0, 0);
    }
    // per-group psum quantize, accumulate into output regs, reset psum
    const float sp  = ps[g];
    const float isp = 1.0f / sp;
#pragma unroll
    for (int i = 0; i < 4; ++i)
#pragma unroll
      for (int j = 0; j < 4; ++j)
#pragma unroll
        for (int k = 0; k < 4; ++k) {
          float q = rintf(acc[i][j][k] * isp);
          q = fminf(127.f, fmaxf(-128.f, q));
          oacc[i][j][k] += q * sp;
          acc[i][j][k] = 0.f;
        }
  }

  // ---- store: D layout col=lane&15 (m), row=(lane>>4)*4+k (oc) ----
  const int ocb = n0 + wr * 64 + ((lane >> 4) << 2);
#pragma unroll
  for (int j = 0; j < 4; ++j) {
    int m = m0 + wc * 64 + j * 16 + rr;
    int b = m / 3136, rem = m - b * 3136;
    int oy = rem / 56, ox = rem - oy * 56;
    int obase = b * 256 * 3136 + oy * 56 + ox;
#pragma unroll
    for (int i = 0; i < 4; ++i)
#pragma unroll
      for (int k = 0; k < 4; ++k)
        out[obase + (ocb + i * 16 + k) * 3136] = oacc[i][j][k];
  }
}

extern "C" void kernel_launch(void* const* d_in, const int* in_sizes, int n_in,
                              void* d_out, int out_size, void* d_ws, size_t ws_size,
                              hipStream_t stream) {
  const float* x   = (const float*)d_in[0];   // [16,256,56,56]
  const float* w   = (const float*)d_in[1];   // [1024,256,3,3]
  const float* wsc = (const float*)d_in[2];   // [8]
  const float* ps  = (const float*)d_in[3];   // [4]
  float* out = (float*)d_out;                 // [16,256,56,56]
  bf16_t* wq = (bf16_t*)d_ws;
  bf16_t* xt = (bf16_t*)((char*)d_ws + WS_XT_OFF);

  quant_w_k<<<9216, 256, 0, stream>>>(w, wsc, wq);      // 1024*9*256 / 256
  pad_x_k<<<16 * 58, 256, 0, stream>>>(x, xt);
  conv_q_k<<<784, 256, 0, stream>>>(xt, wq, ps, out);
}

// Round 2
// 331.416 us; speedup vs baseline: 1.4415x; 1.4415x over previous
//
#include <hip/hip_runtime.h>
#include <stdint.h>
#include <stddef.h>

// SplitConv4Pim forward on MI355X.
// Reference = 1024-channel 3x3 conv (all 4 groups share the same input) with
// 2-bit-slice weight quantization and per-group psum quantization.
//
// ws layout: [wq bf16: 1024*9*256*2 = 4,718,592 B][xt bf16: 16*58*58*256*2 = 27,557,888 B]

typedef __bf16 bf16_t;
typedef __bf16 bf16x8 __attribute__((ext_vector_type(8)));
typedef float  f32x4  __attribute__((ext_vector_type(4)));

#define WS_XT_OFF 4718592

__device__ __forceinline__ void gload16(const void* g, void* l) {
  __builtin_amdgcn_global_load_lds(
      (const __attribute__((address_space(1))) uint32_t*)g,
      (__attribute__((address_space(3))) uint32_t*)l, 16, 0, 0);
}

// ---- P1: weight quantization: w[o][ic][ky][kx] f32 -> wq[o][kpos][ic] bf16 ----
__global__ void quant_w_k(const float* __restrict__ w,
                          const float* __restrict__ wsc,
                          bf16_t* __restrict__ wqo) {
  int idx = blockIdx.x * 256 + threadIdx.x;   // exactly 1024*9*256 threads
  int ic   = idx & 255;
  int t2   = idx >> 8;
  int kpos = t2 % 9;
  int o    = t2 / 9;
  float s  = wsc[ic >> 5];                    // per-32-ic col_slide scale
  float wv = w[o * 2304 + ic * 9 + kpos];
  float wi = rintf(wv / s);                   // jnp.round = RNE = rintf
  wi = fminf(127.f, fmaxf(-128.f, wi));
  int u = (int)wi + 128;                      // unsigned code in [0,255]
  int q = (u >> 6) & 3;                       // bit-slice (shift=64, mask=4)
  float wsplit = (float)(q * 64 - 128);       // minus `move` (IDX==0)
  wqo[idx] = (bf16_t)(wsplit * s);
}

// ---- P2: x NCHW f32 -> padded NHWC bf16 xt[16][58][58][256] ----
__global__ void pad_x_k(const float* __restrict__ x, bf16_t* __restrict__ xt) {
  __shared__ bf16_t tile[56 * 258];           // [x][c], stride 258 kills bank conflicts
  int b  = blockIdx.x / 58;
  int yo = blockIdx.x % 58;
  int t  = threadIdx.x;                       // 256 threads
  bf16_t* dst = xt + (size_t)(b * 58 + yo) * 58 * 256;
  if (yo == 0 || yo == 57) {                  // top/bottom pad rows
    for (int i = 0; i < 58; ++i) dst[i * 256 + t] = (bf16_t)0.0f;
    return;
  }
  const float* src = x + (size_t)b * 256 * 3136 + (yo - 1) * 56;  // + c*3136 + xx
  for (int i = 0; i < 56 * 256; i += 256) {
    int lin = i + t;
    int c  = lin / 56;
    int xx = lin - c * 56;
    tile[xx * 258 + c] = (bf16_t)src[c * 3136 + xx];
  }
  __syncthreads();
  for (int xo = 0; xo < 58; ++xo) {
    bf16_t v = (bf16_t)0.0f;
    if (xo >= 1 && xo <= 56) v = tile[(xo - 1) * 258 + t];
    dst[xo * 256 + t] = v;                    // coalesced 512B stores
  }
}

// ---- main: implicit-GEMM conv + per-group psum quant + group sum ----
// grid: 392 m-tiles * 2 oc-tiles = 784 blocks, 512 threads (8 waves, 2oc x 4m of 64x32).
// BK=64 staged as two [128][32] half-panels; 2 blocks/CU (64 KB LDS, <=128 regs).
__global__ __launch_bounds__(512, 4)
void conv_q_k(const bf16_t* __restrict__ xt, const bf16_t* __restrict__ wq,
              const float* __restrict__ ps, float* __restrict__ out) {
  __shared__ alignas(16) bf16_t Ab[2][2][4096];  // [buf][khalf][128 oc x 32 k]
  __shared__ alignas(16) bf16_t Bb[2][2][4096];  // [buf][khalf][128 m  x 32 k]

  const int tid  = threadIdx.x;
  const int lane = tid & 63;
  const int wave = tid >> 6;

  // T1: XCD-aware swizzle. 784 blocks = 8 XCD chunks x 98. n-major chunking:
  // chunks 0..3 -> oc-half 0, 4..7 -> oc-half 1 (weight panel 2.36 MB fits L2).
  const int bid  = blockIdx.x;
  const int s    = (bid & 7) * 98 + (bid >> 3);
  const int nsel = (s >= 392) ? 1 : 0;
  const int n0   = nsel << 7;                        // oc tile base within group
  const int m0   = (s - nsel * 392) << 7;            // m tile base

  // ---- staging mapping: thread t stages 16B chunk t of each 8 KB half-panel ----
  const int r0   = tid >> 2;                         // row 0..127
  const int subo = (tid & 3) << 3;                   // element offset of 16B chunk
  int rb;                                            // x row base (elems, incl subo)
  {
    int gm = m0 + r0;
    int b = gm / 3136, rem = gm - b * 3136;
    int oy = rem / 56, ox = rem - oy * 56;
    rb = (((b * 58 + oy) * 58 + ox) << 8) + subo;
  }
  const int wrow = (n0 + r0) * 2304 + subo;          // weight row base (elems)
  char* const ldA = (char*)&Ab[0][0][0] + tid * 16;  // wave-uniform base + lane*16
  char* const ldB = (char*)&Bb[0][0][0] + tid * 16;

  // ---- compute mapping: wave = 2 oc-halves x 4 m-quarters, per-wave 64oc x 32m ----
  const int wr = wave >> 2, wc = wave & 3;
  const int rr = lane & 15;
  const int ko = (lane >> 4) << 3;                   // k sub-block 0/8/16/24
  const int aoff = (wr * 64 + rr) * 32 + ko;
  const int boff = (wc * 32 + rr) * 32 + ko;

  f32x4 acc[4][2], oacc[4][2];
#pragma unroll
  for (int i = 0; i < 4; ++i)
#pragma unroll
    for (int j = 0; j < 2; ++j)
#pragma unroll
      for (int k = 0; k < 4; ++k) { acc[i][j][k] = 0.f; oacc[i][j][k] = 0.f; }

  // kk in [0,36): kpos = kk>>2 (tap 0..8), ic-block pair = (kk&3)*2
  auto STAGE = [&](int gg, int kk, int buf) {
    const int kpos = kk >> 2;
    const int ky = kpos / 3;
    const int kx = kpos - ky * 3;
    const int cm = (kk & 3) << 6;                    // first half's ic offset (elems)
    const int wb = wrow + gg * 589824 + kpos * 256 + cm;
    const int xb = rb + ((ky * 58 + kx) << 8) + cm;
    char* la = ldA + buf * 16384;
    char* lb = ldB + buf * 16384;
    gload16(wq + wb,      la);                       // A half 0
    gload16(wq + wb + 32, la + 8192);                // A half 1
    gload16(xt + xb,      lb);                       // B half 0
    gload16(xt + xb + 32, lb + 8192);                // B half 1
  };

  STAGE(0, 0, 0);

#pragma unroll 1
  for (int g = 0; g < 4; ++g) {
#pragma unroll 2
    for (int kk = 0; kk < 36; ++kk) {
      const int buf = kk & 1;
      __syncthreads();                               // drains vmcnt: buf ready, buf^1 free
      if (kk + 1 < 36)      STAGE(g, kk + 1, buf ^ 1);
      else if (g < 3)       STAGE(g + 1, 0, buf ^ 1);
#pragma unroll
      for (int h = 0; h < 2; ++h) {
        const bf16_t* Abase = &Ab[buf][h][aoff];
        const bf16_t* Bbase = &Bb[buf][h][boff];
        bf16x8 av[4], bv[2];
#pragma unroll
        for (int i = 0; i < 4; ++i) av[i] = *(const bf16x8*)(Abase + i * 512);
#pragma unroll
        for (int j = 0; j < 2; ++j) bv[j] = *(const bf16x8*)(Bbase + j * 512);
#pragma unroll
        for (int i = 0; i < 4; ++i)
#pragma unroll
          for (int j = 0; j < 2; ++j)
            acc[i][j] = __builtin_amdgcn_mfma_f32_16x16x32_bf16(av[i], bv[j], acc[i][j], 0, 0, 0);
      }
    }
    // per-group psum quantize, accumulate into output regs, reset psum
    const float sp  = ps[g];
    const float isp = 1.0f / sp;
#pragma unroll
    for (int i = 0; i < 4; ++i)
#pragma unroll
      for (int j = 0; j < 2; ++j)
#pragma unroll
        for (int k = 0; k < 4; ++k) {
          float q = rintf(acc[i][j][k] * isp);
          q = fminf(127.f, fmaxf(-128.f, q));
          oacc[i][j][k] += q * sp;
          acc[i][j][k] = 0.f;
        }
  }

  // ---- store: D layout col=lane&15 (m), row=(lane>>4)*4+k (oc) ----
  const int ocb = n0 + wr * 64 + ((lane >> 4) << 2);
#pragma unroll
  for (int j = 0; j < 2; ++j) {
    int m = m0 + wc * 32 + j * 16 + rr;
    int b = m / 3136, rem = m - b * 3136;
    int oy = rem / 56, ox = rem - oy * 56;
    int obase = b * 802816 + oy * 56 + ox;
#pragma unroll
    for (int i = 0; i < 4; ++i)
#pragma unroll
      for (int k = 0; k < 4; ++k)
        out[obase + (ocb + i * 16 + k) * 3136] = oacc[i][j][k];
  }
}

extern "C" void kernel_launch(void* const* d_in, const int* in_sizes, int n_in,
                              void* d_out, int out_size, void* d_ws, size_t ws_size,
                              hipStream_t stream) {
  const float* x   = (const float*)d_in[0];   // [16,256,56,56]
  const float* w   = (const float*)d_in[1];   // [1024,256,3,3]
  const float* wsc = (const float*)d_in[2];   // [8]
  const float* ps  = (const float*)d_in[3];   // [4]
  float* out = (float*)d_out;                 // [16,256,56,56]
  bf16_t* wq = (bf16_t*)d_ws;
  bf16_t* xt = (bf16_t*)((char*)d_ws + WS_XT_OFF);

  quant_w_k<<<9216, 256, 0, stream>>>(w, wsc, wq);
  pad_x_k<<<16 * 58, 256, 0, stream>>>(x, xt);
  conv_q_k<<<784, 512, 0, stream>>>(xt, wq, ps, out);
}